// Round 4
// baseline (273.709 us; speedup 1.0000x reference)
//
#include <hip/hip_runtime.h>

// Problem constants (B=8, S=256, F=16384, K=32)
#define N_ELEMS  33554432   // 8*256*16384
#define N_TOKENS 2048
#define F4       4096       // float4 per token
#define K_TOTAL  65536u     // K * B * S
#define NBINS    4096       // fine bins over key range [0xC0000000, 0xC1000000) == f in [2,8)
                            // bin width ~0.001 at cutoff (f~2.66) => ~190 elems in cutoff bin

// ws layout (uint32 word indices)
#define C_NG       4096     // gated-list counter
#define C_WINTH    4097     // winner threshold (key >= -> definitely selected)
#define C_CANDTH   4098     // candidate threshold (cutoff-bin lower edge)
#define C_NEED     4099     // how many to take from the cutoff bin
#define C_FB       4100     // fallback flag
#define C_N2       4101     // cutoff-bin candidate counter
#define N_CTR_END  4160

#define GLIST_OFF  8192u    // uint2: all gated (f>=2) elements, (key, flat_idx)
#define CAPG       4194304u // expected ~380K; overflow -> fallback
#define LIST2_OFF  (GLIST_OFF + 2u*CAPG)
#define CAP2       4096u    // cutoff-bin candidates (expected ~190)
#define FB1_OFF    16777216u  // fallback scratch lists (correctness-only path)
#define CAPF       2097152u
#define FB2_OFF    (FB1_OFF + 2u*CAPF)

typedef float v4f __attribute__((ext_vector_type(4)));

// Order-preserving fp32 -> u32 map (larger float <=> larger key)
__device__ __forceinline__ unsigned keyOf(float f) {
    unsigned b = __float_as_uint(f);
    return b ^ ((unsigned)((int)b >> 31) | 0x80000000u);
}
__device__ __forceinline__ float valOf(unsigned u) {
    unsigned b = (u & 0x80000000u) ? (u ^ 0x80000000u) : ~u;
    return __uint_as_float(b);
}
__device__ __forceinline__ unsigned umaxu(unsigned a, unsigned b) { return a > b ? a : b; }

// ---------------- init: zero fine bins + counters (ws poisoned 0xAA every call)
__global__ void k_init(unsigned* __restrict__ ws) {
    int t = blockIdx.x * 256 + threadIdx.x;
    if (t < N_CTR_END) ws[t] = 0u;
}

// ---------------- pass 1 (the ONLY full read of x): fine gated histogram
// + compact gated elements to global list + dense-zero this token's output.
#define GBUF 1024
__global__ __launch_bounds__(512) void k_hist(const float4* __restrict__ x,
                                              const int* __restrict__ mask,
                                              unsigned* __restrict__ ws,
                                              float4* __restrict__ out) {
    __shared__ unsigned lh[NBINS];     // 16 KB
    __shared__ uint2 sbuf[GBUF];       // 8 KB staging for compaction
    __shared__ unsigned s_cnt, s_base;
    const int tok = blockIdx.x;
    v4f* ot = (v4f*)(out + (size_t)tok * F4);
    const v4f z = {0.f, 0.f, 0.f, 0.f};
    if (!mask[tok]) {                  // masked token: zero output (nt), no x read
        for (int j = threadIdx.x; j < F4; j += 512)
            __builtin_nontemporal_store(z, &ot[j]);
        return;
    }
    for (int b = threadIdx.x; b < NBINS; b += 512) lh[b] = 0u;
    if (threadIdx.x == 0) s_cnt = 0u;
    __syncthreads();
    uint2* glist = (uint2*)(ws + GLIST_OFF);
    const float4* xt = x + (size_t)tok * F4;
    const unsigned baseIdx = (unsigned)tok * 16384u;
    for (int j = threadIdx.x; j < F4; j += 512) {
        float4 v = xt[j];
        __builtin_nontemporal_store(z, &ot[j]);   // fused dense zero (winners fixed later)
        // pre-filter: ~91% of float4s have no gated component
        if (fmaxf(fmaxf(v.x, v.y), fmaxf(v.z, v.w)) >= 2.0f) {
            float fv[4] = {v.x, v.y, v.z, v.w};
            #pragma unroll
            for (int c = 0; c < 4; c++) {
                float f = fv[c];
                if (f >= 2.0f) {       // ~2.3% of elements; cutoff ~2.66 for this input
                    unsigned u = keyOf(f);
                    unsigned bin = (u - 0xC0000000u) >> 12;
                    if (bin > 4095u) bin = 4095u;  // f>=8 clamps to top bin
                    atomicAdd(&lh[bin], 1u);
                    unsigned slot = atomicAdd(&s_cnt, 1u);
                    uint2 e = make_uint2(u, baseIdx + (unsigned)j * 4u + (unsigned)c);
                    if (slot < GBUF) sbuf[slot] = e;
                    else { unsigned g = atomicAdd(&ws[C_NG], 1u); if (g < CAPG) glist[g] = e; }
                }
            }
        }
    }
    __syncthreads();
    for (int b = threadIdx.x; b < NBINS; b += 512) {
        unsigned c = lh[b];
        if (c) atomicAdd(&ws[b], c);   // ~350 nonzero bins/block
    }
    unsigned cnt = s_cnt; if (cnt > GBUF) cnt = GBUF;   // expected ~373/block
    if (threadIdx.x == 0) s_base = atomicAdd(&ws[C_NG], cnt);  // one bulk atomic/block
    __syncthreads();
    for (unsigned j = threadIdx.x; j < cnt; j += 512) {
        unsigned p = s_base + j;
        if (p < CAPG) glist[p] = sbuf[j];
    }
}

// ---------------- scan: suffix-scan 4096 fine bins -> thresholds, need, fallback flag
__global__ __launch_bounds__(1024) void k_scan1(unsigned* __restrict__ ws) {
    __shared__ unsigned sc[1024];
    __shared__ unsigned sB1, sKA, sFound;
    const int t = threadIdx.x;
    unsigned vv[4];
    unsigned s = 0u;
    #pragma unroll
    for (int j = 0; j < 4; ++j) { vv[j] = ws[t * 4 + j]; s += vv[j]; }
    if (t == 0) sFound = 0u;
    sc[t] = s;
    __syncthreads();
    for (int off = 1; off < 1024; off <<= 1) {
        unsigned a = sc[t];
        unsigned b = (t + off < 1024) ? sc[t + off] : 0u;
        __syncthreads();
        sc[t] = a + b;
        __syncthreads();
    }
    unsigned run = (t < 1023) ? sc[t + 1] : 0u;      // cntGE(first bin of next chunk)
    #pragma unroll
    for (int j = 3; j >= 0; --j) {
        unsigned prev = run; run += vv[j];           // run = cntGE(bin t*4+j)
        if (run >= K_TOTAL && prev < K_TOTAL) {      // unique crossing
            sB1 = (unsigned)(t * 4 + j); sKA = prev; sFound = 1u;
        }
    }
    __syncthreads();
    if (t == 0) {
        unsigned total = sc[0];
        unsigned ng = ws[C_NG];
        unsigned fb = (sFound == 0u) || (total < K_TOTAL) || (sB1 == 4095u) || (ng > CAPG);
        ws[C_FB] = fb ? 1u : 0u;
        if (!fb) {
            unsigned candTh = 0xC0000000u + (sB1 << 12);
            ws[C_CANDTH] = candTh;
            ws[C_WINTH]  = candTh + 0x1000u;
            ws[C_NEED]   = K_TOTAL - sKA;
        }
    }
}

// ---------------- scatter winners from the compact gated list (no x re-read)
__global__ __launch_bounds__(256) void k_scatter(unsigned* __restrict__ ws,
                                                 float* __restrict__ out) {
    if (ws[C_FB]) return;
    const unsigned winTh = ws[C_WINTH], candTh = ws[C_CANDTH];
    unsigned ng = ws[C_NG]; if (ng > CAPG) ng = CAPG;
    uint2* glist = (uint2*)(ws + GLIST_OFF);
    uint2* list2 = (uint2*)(ws + LIST2_OFF);
    const unsigned stride = gridDim.x * 256;
    for (unsigned i = blockIdx.x * 256 + threadIdx.x; i < ng; i += stride) {
        uint2 e = glist[i];
        if (e.x >= winTh) out[e.y] = valOf(e.x);     // >= 2.0 > 0: relu moot
        else if (e.x >= candTh) {                    // cutoff bin (~190 total)
            unsigned g = atomicAdd(&ws[C_N2], 1u);
            if (g < CAP2) list2[g] = e;
        }
    }
}

// ---------------- tail + fallback merged (single block):
// fast path: exact rank among ~190 cutoff-bin candidates + EMA threshold.
// fallback path: full exact algorithm (never runs for this input; correctness-only).
__global__ __launch_bounds__(1024) void k_tailfb(const float4* __restrict__ x,
                                                 const int* __restrict__ mask,
                                                 unsigned* __restrict__ ws,
                                                 float* __restrict__ out,
                                                 const float* __restrict__ thr) {
    __shared__ unsigned lh[NBINS];     // 16 KB (fallback hist)
    __shared__ uint2 ent[CAP2];        // 32 KB (fast-path tie entries)
    __shared__ unsigned sred[1024];
    __shared__ unsigned sB1, sKA, sMode, sNegmin, sB2, sNeed, sCnt;
    const int t = threadIdx.x;
    unsigned fb = ws[C_FB];

    if (!fb) {
        unsigned rawn2 = ws[C_N2];
        if (rawn2 <= CAP2) {
            // -------- fast path --------
            const unsigned n2 = rawn2;
            const unsigned need = ws[C_NEED];   // n2 >= need >= 1 by construction
            uint2* list2 = (uint2*)(ws + LIST2_OFF);
            for (unsigned i = t; i < n2; i += 1024) ent[i] = list2[i];
            __syncthreads();
            unsigned minSel = 0xFFFFFFFFu;
            for (unsigned i = t; i < n2; i += 1024) {
                uint2 e = ent[i];
                unsigned rank = 0u;
                for (unsigned j = 0; j < n2; ++j) {   // ties -> lower idx (lax.top_k)
                    uint2 o = ent[j];
                    rank += (o.x > e.x || (o.x == e.x && o.y < e.y)) ? 1u : 0u;
                }
                if (rank < need) {
                    out[e.y] = valOf(e.x);
                    if (e.x < minSel) minSel = e.x;
                }
            }
            sred[t] = minSel;
            __syncthreads();
            for (int off = 512; off > 0; off >>= 1) {
                if (t < off) sred[t] = sred[t] < sred[t + off] ? sred[t] : sred[t + off];
                __syncthreads();
            }
            if (t == 0)   // min selected = k-th largest >= 2.0 > 0 == min_pos
                out[N_ELEMS] = 0.99f * thr[0] + 0.01f * valOf(sred[0]);
            return;
        }
        // overflow: fall through to exact fallback
    }

    // -------- fallback: full exact algorithm --------
    for (int b = t; b < NBINS; b += 1024) lh[b] = 0u;
    __syncthreads();
    unsigned negmin = 0u;              // max(~key) over positive values
    for (int tok = 0; tok < N_TOKENS; ++tok) {
        if (!mask[tok]) continue;
        const float4* xt = x + (size_t)tok * F4;
        for (int j = t; j < F4; j += 1024) {
            float4 v = xt[j];
            float fv[4] = {v.x, v.y, v.z, v.w};
            #pragma unroll
            for (int c = 0; c < 4; ++c) {
                float f = fv[c];
                unsigned u = keyOf(f);
                atomicAdd(&lh[u >> 20], 1u);   // coarse 12-bit bins
                if (f > 0.0f) negmin = umaxu(negmin, ~u);
            }
        }
    }
    __syncthreads();
    sred[t] = negmin; __syncthreads();
    for (int off = 512; off > 0; off >>= 1) {
        if (t < off) sred[t] = umaxu(sred[t], sred[t + off]);
        __syncthreads();
    }
    if (t == 0) {
        sNegmin = sred[0];
        unsigned tot = 0u;
        for (int b = 0; b < NBINS; ++b) tot += lh[b];
        if (tot <= K_TOTAL) sMode = 1u;          // select ALL unmasked elements
        else {
            sMode = 0u;
            unsigned run = 0u, prev = 0u; int b1 = 0;
            for (int b = NBINS - 1; b >= 0; --b) {
                prev = run; run += lh[b];
                if (run >= K_TOTAL && prev < K_TOTAL) { b1 = b; break; }
            }
            sB1 = (unsigned)b1; sKA = prev;
        }
        sCnt = 0u;
    }
    __syncthreads();
    if (sMode == 1u) {
        for (int tok = 0; tok < N_TOKENS; ++tok) {
            if (!mask[tok]) continue;
            const float4* xt = x + (size_t)tok * F4;
            float* ot = out + (size_t)tok * 16384;
            for (int j = t; j < F4; j += 1024) {
                float4 v = xt[j];
                ot[j * 4 + 0] = fmaxf(v.x, 0.f); ot[j * 4 + 1] = fmaxf(v.y, 0.f);
                ot[j * 4 + 2] = fmaxf(v.z, 0.f); ot[j * 4 + 3] = fmaxf(v.w, 0.f);
            }
        }
        if (t == 0) {
            float th = thr[0], newt = th;
            if (sNegmin) newt = 0.99f * th + 0.01f * valOf(~sNegmin);
            out[N_ELEMS] = newt;
        }
        return;
    }
    // scatter coarse winners; compact coarse cutoff bin
    const unsigned B1c = sB1;
    uint2* fb1 = (uint2*)(ws + FB1_OFF);
    for (int tok = 0; tok < N_TOKENS; ++tok) {
        if (!mask[tok]) continue;
        const float4* xt = x + (size_t)tok * F4;
        const unsigned baseIdx = (unsigned)tok * 16384u;
        for (int j = t; j < F4; j += 1024) {
            float4 v = xt[j];
            float fv[4] = {v.x, v.y, v.z, v.w};
            #pragma unroll
            for (int c = 0; c < 4; ++c) {
                float f = fv[c];
                unsigned u = keyOf(f);
                unsigned p = u >> 20;
                unsigned idx = baseIdx + (unsigned)j * 4u + (unsigned)c;
                if (p > B1c) out[idx] = fmaxf(f, 0.f);
                else if (p == B1c) {
                    unsigned g = atomicAdd(&sCnt, 1u);
                    if (g < CAPF) fb1[g] = make_uint2(u, idx);
                }
            }
        }
    }
    __syncthreads();
    unsigned n1 = sCnt > CAPF ? CAPF : sCnt;
    __syncthreads();
    if (t < 256) lh[t] = 0u;           // reuse as 8-bit refine histogram
    if (t == 0) sCnt = 0u;
    __syncthreads();
    for (unsigned i = t; i < n1; i += 1024)
        atomicAdd(&lh[(fb1[i].x >> 12) & 255u], 1u);
    __syncthreads();
    if (t == 0) {
        unsigned run = sKA, prev = sKA; int b2 = 0;
        for (int b = 255; b >= 0; --b) {
            prev = run; run += lh[b];
            if (run >= K_TOTAL) { b2 = b; break; }
        }
        sB2 = (unsigned)b2; sNeed = K_TOTAL - prev;
    }
    __syncthreads();
    const unsigned B2 = sB2, need = sNeed;
    uint2* fb2 = (uint2*)(ws + FB2_OFF);
    for (unsigned i = t; i < n1; i += 1024) {
        uint2 e = fb1[i];
        unsigned bb = (e.x >> 12) & 255u;
        if (bb > B2) out[e.y] = fmaxf(valOf(e.x), 0.f);
        else if (bb == B2) {
            unsigned g = atomicAdd(&sCnt, 1u);
            if (g < CAPF) fb2[g] = e;
        }
    }
    __syncthreads();
    unsigned n2f = sCnt > CAPF ? CAPF : sCnt;
    unsigned minSel = 0xFFFFFFFFu;
    for (unsigned i = t; i < n2f; i += 1024) {
        uint2 e = fb2[i];
        unsigned rank = 0u;
        for (unsigned jj = 0; jj < n2f; ++jj) {
            uint2 o = fb2[jj];
            rank += (o.x > e.x || (o.x == e.x && o.y < e.y)) ? 1u : 0u;
        }
        if (rank < need) { out[e.y] = fmaxf(valOf(e.x), 0.f); if (e.x < minSel) minSel = e.x; }
    }
    __syncthreads();
    sred[t] = minSel; __syncthreads();
    for (int off = 512; off > 0; off >>= 1) {
        if (t < off) sred[t] = sred[t] < sred[t + off] ? sred[t] : sred[t + off];
        __syncthreads();
    }
    if (t == 0) {
        float th = thr[0], newt = th;
        unsigned vku = sred[0];
        if (vku != 0xFFFFFFFFu) {
            float vk = valOf(vku);
            float minpos; int any;
            if (vk > 0.f) { minpos = vk; any = 1; }
            else { any = (sNegmin != 0u); minpos = any ? valOf(~sNegmin) : 0.f; }
            if (any) newt = 0.99f * th + 0.01f * minpos;
        }
        out[N_ELEMS] = newt;
    }
}

extern "C" void kernel_launch(void* const* d_in, const int* in_sizes, int n_in,
                              void* d_out, int out_size, void* d_ws, size_t ws_size,
                              hipStream_t stream) {
    const float4* x  = (const float4*)d_in[0];
    const int* mask  = (const int*)d_in[1];
    const float* thr = (const float*)d_in[2];
    float* out       = (float*)d_out;
    unsigned* ws     = (unsigned*)d_ws;

    k_init   <<<17, 256, 0, stream>>>(ws);
    k_hist   <<<N_TOKENS, 512, 0, stream>>>(x, mask, ws, (float4*)out);
    k_scan1  <<<1, 1024, 0, stream>>>(ws);
    k_scatter<<<256, 256, 0, stream>>>(ws, out);
    k_tailfb <<<1, 1024, 0, stream>>>(x, mask, ws, out, thr);
}